// Round 8
// baseline (1650.951 us; speedup 1.0000x reference)
//
#include <hip/hip_runtime.h>

// ============================================================================
// Wired CfC (NCP) scan, B=256 x T=1024, 3 layers (hid 135/89/32) + final FC.
//
// Round 12: delivery-pipe balance. r9/r8/r11 each dumped the ~250-300KB/tick
// weight stream onto ONE pipe (L2-scratch 56B/cyc, or LDS 85B/cyc) -> tick
// 3.6-4.0k cyc, all consistent with tick = delivery + ~700 tail. Balance:
//  - clone0 (L0 h-part, after U x-precompute): W1/W2/Wa ALL in regs (108dw,
//    ~8dw spill -> L2 pipe). wa0 LDS eliminated.
//  - clone1 (generic, units 128-223): W1/W2 regs (112dw, ~15dw spill -> L2),
//    Wa from LDS (14 b128/lane/tick).
//  - clone2 (L2, K=121): fully reg-resident (96dw), zero spill, zero wa-LDS.
//  - DPP reinstated (dropped in r11): x-block pair-share via quad_perm
//    (halves x LDS reads; wave 4 direct for the layer-straddling quad) and
//    pair_sum DPP instead of __shfl_xor (removes 120cyc ds_bpermute tail).
//  - U packed [WIN][128][4] f16 -> one ds_read_b64 per lane per tick.
// LDS ~1600cyc + L2 ~390 (parallel) + VALU ~720 (parallel) -> tick 2300-2700.
// Predict: dur 950-1250us, WRITE <10MB, conflicts 86M -> 40-60M.
// ============================================================================

typedef _Float16 half2v __attribute__((ext_vector_type(2)));
typedef _Float16 half4v __attribute__((ext_vector_type(4)));
typedef _Float16 half8v __attribute__((ext_vector_type(8)));
typedef int      int4v  __attribute__((ext_vector_type(4)));

#define NBLK   256
#define NTHR   512
#define TSTEPS 1024
#define KPAD   224
#define WIN    64

struct Ptrs {
    const float* x;
    const unsigned int* msk[3];
    const float* W1[3];
    const float* W2[3];
    const float* Wa[3];
    const float* Wb[3];
    const float* b1[3];
    const float* b2[3];
    const float* ba[3];
    const float* bb[3];
    const float* fcW;
    const float* fcb;
};

__device__ __forceinline__ float fexp2(float x) {
#if __has_builtin(__builtin_amdgcn_exp2f)
    return __builtin_amdgcn_exp2f(x);
#else
    return exp2f(x);
#endif
}
__device__ __forceinline__ float frcp(float x) {
#if __has_builtin(__builtin_amdgcn_rcpf)
    return __builtin_amdgcn_rcpf(x);
#else
    return 1.0f / x;
#endif
}
__device__ __forceinline__ float fsig(float x) {
    return frcp(1.0f + fexp2(-1.442695041f * x));
}
__device__ __forceinline__ float ftanh(float x) {
    return 2.0f * frcp(1.0f + fexp2(-2.885390082f * x)) - 1.0f;
}

#if __has_builtin(__builtin_amdgcn_fdot2)
#define FD(a, b, c) __builtin_amdgcn_fdot2((a), (b), (c), false)
#else
__device__ __forceinline__ float fd_fallback(half2v a, half2v b, float c) {
    return c + (float)a[0] * (float)b[0] + (float)a[1] * (float)b[1];
}
#define FD(a, b, c) fd_fallback((a), (b), (c))
#endif

__device__ __forceinline__ half2v h2(_Float16 a, _Float16 b) { return half2v{a, b}; }

// quad_perm(2,3,0,1): fetch lane^2's value (unit partner within quad). VALU.
__device__ __forceinline__ half8v dpp_xor2(half8v v) {
    int4v a = __builtin_bit_cast(int4v, v);
    int4v r;
    r[0] = __builtin_amdgcn_update_dpp(0, a[0], 0x4E, 0xF, 0xF, true);
    r[1] = __builtin_amdgcn_update_dpp(0, a[1], 0x4E, 0xF, 0xF, true);
    r[2] = __builtin_amdgcn_update_dpp(0, a[2], 0x4E, 0xF, 0xF, true);
    r[3] = __builtin_amdgcn_update_dpp(0, a[3], 0x4E, 0xF, 0xF, true);
    return __builtin_bit_cast(half8v, r);
}
// quad_perm(1,0,3,2): x + lane^1's x (K-half pair combine). VALU.
__device__ __forceinline__ float pair_sum(float x) {
    const int v = __builtin_amdgcn_update_dpp(
        0, __builtin_bit_cast(int, x), 0xB1, 0xF, 0xF, true);
    return x + __builtin_bit_cast(float, v);
}

// masked fold (sparse region) and no-mask / Wa+Wb folds, all K-guarded.
__device__ __forceinline__ half2v fold2(const float* Wp, const unsigned int* mkp,
                                        int nK, int K, int k0) {
    float u0 = 0.f, u1 = 0.f;
    if (k0 < K)     { u0 = Wp[nK + k0]     * ((mkp[nK + k0]     != 0u) ? 1.0f : 0.0f); }
    if (k0 + 1 < K) { u1 = Wp[nK + k0 + 1] * ((mkp[nK + k0 + 1] != 0u) ? 1.0f : 0.0f); }
    return h2((_Float16)u0, (_Float16)u1);
}
__device__ __forceinline__ half2v nm2(const float* Wp, int nK, int K, int k0) {
    float u0 = (k0 < K)     ? Wp[nK + k0]     : 0.0f;
    float u1 = (k0 + 1 < K) ? Wp[nK + k0 + 1] : 0.0f;
    return h2((_Float16)u0, (_Float16)u1);
}
__device__ __forceinline__ half2v na2(const float* Wa, const float* Wb,
                                      int nK, int K, int k0) {
    float u0 = (k0 < K)     ? Wa[nK + k0]     + Wb[nK + k0]     : 0.0f;
    float u1 = (k0 + 1 < K) ? Wa[nK + k0 + 1] + Wb[nK + k0 + 1] : 0.0f;
    return h2((_Float16)u0, (_Float16)u1);
}

// 12 dot2s, wa from REGISTER half2 array
#define DOT12R(xv, w1a, w2a, waa, A, B, C) { \
    const half2v X0 = h2(xv[0], xv[1]), X1 = h2(xv[2], xv[3]); \
    const half2v X2 = h2(xv[4], xv[5]), X3 = h2(xv[6], xv[7]); \
    A = FD(X0, (w1a)[0], A); B = FD(X0, (w2a)[0], B); C = FD(X0, (waa)[0], C); \
    A = FD(X1, (w1a)[1], A); B = FD(X1, (w2a)[1], B); C = FD(X1, (waa)[1], C); \
    A = FD(X2, (w1a)[2], A); B = FD(X2, (w2a)[2], B); C = FD(X2, (waa)[2], C); \
    A = FD(X3, (w1a)[3], A); B = FD(X3, (w2a)[3], B); C = FD(X3, (waa)[3], C); }

// 12 dot2s, wa from an LDS-loaded half8v
#define DOT12L(xv, w1a, w2a, wav, A, B, C) { \
    const half2v X0 = h2(xv[0], xv[1]), X1 = h2(xv[2], xv[3]); \
    const half2v X2 = h2(xv[4], xv[5]), X3 = h2(xv[6], xv[7]); \
    A = FD(X0, (w1a)[0], A); B = FD(X0, (w2a)[0], B); C = FD(X0, h2((wav)[0], (wav)[1]), C); \
    A = FD(X1, (w1a)[1], A); B = FD(X1, (w2a)[1], B); C = FD(X1, h2((wav)[2], (wav)[3]), C); \
    A = FD(X2, (w1a)[2], A); B = FD(X2, (w2a)[2], B); C = FD(X2, h2((wav)[4], (wav)[5]), C); \
    A = FD(X3, (w1a)[3], A); B = FD(X3, (w2a)[3], B); C = FD(X3, h2((wav)[6], (wav)[7]), C); }

// One precompute job: x-part dot for layer-0 unit jn, matrix jm, all WIN ticks.
#define DOJOB(jj_) { \
    const int jm = (jj_) >> 7, jn = (jj_) & 127; \
    const float* Wp = (jm == 0) ? P.W1[0] : (jm == 1) ? P.W2[0] : P.Wa[0]; \
    const float* Wq = P.Wb[0]; \
    const unsigned int* mk0 = P.msk[0]; \
    const int base = jn * 199; \
    half2v wrow[32]; \
    _Pragma("unroll") \
    for (int i2 = 0; i2 < 32; ++i2) { \
        const int k = 2 * i2; \
        float v0 = Wp[base + k], v1 = Wp[base + k + 1]; \
        if (jm == 2) { v0 += Wq[base + k]; v1 += Wq[base + k + 1]; } \
        else { \
            v0 = (mk0[base + k] != 0u) ? v0 : 0.0f; \
            v1 = (mk0[base + k + 1] != 0u) ? v1 : 0.0f; \
        } \
        wrow[i2] = h2((_Float16)v0, (_Float16)v1); \
    } \
    for (int ti = 0; ti < WIN; ++ti) { \
        float acc = 0.0f; \
        _Pragma("unroll") \
        for (int q = 0; q < 8; ++q) { \
            const half8v xq = *(const half8v*)&xwin[ti][8 * q]; \
            acc = FD(h2(xq[0], xq[1]), wrow[4 * q + 0], acc); \
            acc = FD(h2(xq[2], xq[3]), wrow[4 * q + 1], acc); \
            acc = FD(h2(xq[4], xq[5]), wrow[4 * q + 2], acc); \
            acc = FD(h2(xq[6], xq[7]), wrow[4 * q + 3], acc); \
        } \
        U[ti][jn][jm] = (_Float16)acc; \
    } \
}

// Window block: 3 barriers in every clone (equal counts across waves).
#define WINDOW_BLOCK(STAGE_, JOBS_) \
    if ((tick & (WIN - 1)) == 0 && tick < TSTEPS) { \
        __syncthreads(); \
        STAGE_ \
        __syncthreads(); \
        JOBS_ \
        __syncthreads(); \
    }

__global__ __launch_bounds__(NTHR)
void cfc_kernel(Ptrs P, float* __restrict__ out) {
    __shared__ __align__(16) _Float16 xc[2][3][KPAD];   //   2688 B
    __shared__ __align__(16) float    hn[256];          //   1024 B
    __shared__ __align__(16) _Float16 U[WIN][128][4];   //  65536 B (jm-packed)
    __shared__ __align__(16) _Float16 wa1[96][232];     //  44544 B (clone1 Wa)
    __shared__ __align__(16) _Float16 xwin[WIN][64];    //   8192 B

    const int tid  = threadIdx.x;
    const int b    = blockIdx.x;
    const int unit = tid >> 1;
    const int half = tid & 1;
    const int up   = unit & 1;   // block-parity this lane reads itself

    // ---- zero xc (common) ----
    {
        int* z = (int*)&xc[0][0][0];
        for (int i = tid; i < 2 * 3 * KPAD / 2; i += NTHR) z[i] = 0;
    }
    __syncthreads();   // barrier #1 (common)

    const size_t rb = (size_t)b * TSTEPS;

    if (tid < 256) {
        // ============== CLONE 0: pure L0, units 0-127 (h-part only) ==============
        const int n = unit;
        const float* W1p = P.W1[0];
        const float* W2p = P.W2[0];
        const float* Wap = P.Wa[0];
        const float* Wbp = P.Wb[0];
        const int nK = n * 199;
        const int cb = 64 + 72 * half;   // column base (h-part, this K-half)

        // weights: 4 own + 4 partner DPP blocks + 1 direct last block = 108 dw
        half2v w1o_[16], w1t_[16], w1l_[4];
        half2v w2o_[16], w2t_[16], w2l_[4];
        half2v wao_[16], wat_[16], wal_[4];
#pragma unroll
        for (int j = 0; j < 4; ++j) {
#pragma unroll
            for (int e = 0; e < 4; ++e) {
                const int co = cb + (2 * j + up) * 8 + 2 * e;
                const int ct = cb + (2 * j + 1 - up) * 8 + 2 * e;
                w1o_[j * 4 + e] = nm2(W1p, nK, 199, co);
                w1t_[j * 4 + e] = nm2(W1p, nK, 199, ct);
                w2o_[j * 4 + e] = nm2(W2p, nK, 199, co);
                w2t_[j * 4 + e] = nm2(W2p, nK, 199, ct);
                wao_[j * 4 + e] = na2(Wap, Wbp, nK, 199, co);
                wat_[j * 4 + e] = na2(Wap, Wbp, nK, 199, ct);
            }
        }
#pragma unroll
        for (int e = 0; e < 4; ++e) {
            const int cl = cb + 64 + 2 * e;
            w1l_[e] = nm2(W1p, nK, 199, cl);
            w2l_[e] = nm2(W2p, nK, 199, cl);
            wal_[e] = na2(Wap, Wbp, nK, 199, cl);
        }
        const float bv1 = P.b1[0][n];
        const float bv2 = P.b2[0][n];
        const float bva = P.ba[0][n] + P.bb[0][n];
        __syncthreads();   // barrier #2

        for (int tick = 0; tick < TSTEPS + 2; ++tick) {
            WINDOW_BLOCK(
                if (tid < 64) {
                    for (int ti = 0; ti < WIN; ++ti)
                        xwin[ti][tid] = (_Float16)P.x[(rb + tick + ti) * 64 + tid];
                },
                { DOJOB(tid); if (tid < 64) { DOJOB(320 + tid); } }
            )
            const int s = tick;
            if (s < TSTEPS) {
                const _Float16* srcp = &xc[s & 1][0][cb];
                float a0 = 0.f, a1 = 0.f, b0 = 0.f, b1 = 0.f, c0 = 0.f, c1 = 0.f;
#pragma unroll
                for (int j = 0; j < 4; ++j) {
                    const half8v xo = *(const half8v*)(srcp + (2 * j + up) * 8);
                    const half8v xt = dpp_xor2(xo);
                    DOT12R(xo, &w1o_[4 * j], &w2o_[4 * j], &wao_[4 * j], a0, b0, c0);
                    DOT12R(xt, &w1t_[4 * j], &w2t_[4 * j], &wat_[4 * j], a1, b1, c1);
                }
                {
                    const half8v xl = *(const half8v*)(srcp + 64);
                    DOT12R(xl, w1l_, w2l_, wal_, a0, b0, c0);
                }
                const half4v uv = *(const half4v*)&U[s & (WIN - 1)][n][0];
                const float s1 = pair_sum(a0 + a1) + (float)uv[0] + bv1;
                const float s2 = pair_sum(b0 + b1) + (float)uv[1] + bv2;
                const float sa = pair_sum(c0 + c1) + (float)uv[2] + bva;
                const float f1 = ftanh(s1);
                const float f2 = ftanh(s2);
                const float tg = fsig(sa);
                const float h  = f1 + tg * (f2 - f1);
                const _Float16 hv = (_Float16)h;
                const int pA = s & 1, pB = (s + 1) & 1;
                if (half == 0) {
                    xc[pA][1][n] = hv;                     // -> layer1 input
                    if (s == TSTEPS - 1) hn[n] = h;
                } else {
                    xc[pB][0][64 + n] = hv;                // own recurrence
                }
            }
            __syncthreads();
        }
    } else if (tid < 448) {
        // ============ CLONE 1: generic, units 128-223 (L0 tail + L1) ============
        int L, n;
        if (unit < 135) { L = 0; n = unit; } else { L = 1; n = unit - 135; }
        const int K    = (L == 0) ? 199 : 224;
        const int HOFF = (L == 0) ? 0 : 135;
        const float* W1p = P.W1[L];
        const float* W2p = P.W2[L];
        const float* Wap = P.Wa[L];
        const float* Wbp = P.Wb[L];
        const unsigned int* mkp = P.msk[L];
        const int nK   = n * K;
        const int koff = 112 * half;
        const int u128 = unit - 128;
        // wave 4 holds the layer-straddling quad (units 134/135) -> direct path
        const bool direct = ((tid >> 6) == 4);

        half2v w1o[28], w1t[28], w2o[28], w2t[28];
#pragma unroll
        for (int j = 0; j < 7; ++j) {
#pragma unroll
            for (int e = 0; e < 4; ++e) {
                const int co = koff + (2 * j + up) * 8 + 2 * e;
                const int ct = koff + (2 * j + 1 - up) * 8 + 2 * e;
                w1o[j * 4 + e] = fold2(W1p, mkp, nK, K, co);
                w1t[j * 4 + e] = fold2(W1p, mkp, nK, K, ct);
                w2o[j * 4 + e] = fold2(W2p, mkp, nK, K, co);
                w2t[j * 4 + e] = fold2(W2p, mkp, nK, K, ct);
                *(half2v*)&wa1[u128][co] = na2(Wap, Wbp, nK, K, co);
                *(half2v*)&wa1[u128][ct] = na2(Wap, Wbp, nK, K, ct);
            }
        }
        const float bv1 = P.b1[L][n];
        const float bv2 = P.b2[L][n];
        const float bva = P.ba[L][n] + P.bb[L][n];
        __syncthreads();   // barrier #2

        for (int tick = 0; tick < TSTEPS + 2; ++tick) {
            WINDOW_BLOCK(;, ;)
            const int s = tick - L;
            if (s >= 0 && s < TSTEPS) {
                const _Float16* srcp = &xc[s & 1][L][koff];
                const _Float16* wap  = &wa1[u128][koff];
                float a0 = 0.f, a1 = 0.f, b0 = 0.f, b1 = 0.f, c0 = 0.f, c1 = 0.f;
                if (!direct) {
#pragma unroll
                    for (int j = 0; j < 7; ++j) {
                        const half8v xo = *(const half8v*)(srcp + (2 * j + up) * 8);
                        const half8v xt = dpp_xor2(xo);
                        const half8v wo = *(const half8v*)(wap + (2 * j + up) * 8);
                        const half8v wt = *(const half8v*)(wap + (2 * j + 1 - up) * 8);
                        DOT12L(xo, &w1o[4 * j], &w2o[4 * j], wo, a0, b0, c0);
                        DOT12L(xt, &w1t[4 * j], &w2t[4 * j], wt, a1, b1, c1);
                    }
                } else {
#pragma unroll
                    for (int j = 0; j < 7; ++j) {
                        const half8v xo = *(const half8v*)(srcp + (2 * j + up) * 8);
                        const half8v xt = *(const half8v*)(srcp + (2 * j + 1 - up) * 8);
                        const half8v wo = *(const half8v*)(wap + (2 * j + up) * 8);
                        const half8v wt = *(const half8v*)(wap + (2 * j + 1 - up) * 8);
                        DOT12L(xo, &w1o[4 * j], &w2o[4 * j], wo, a0, b0, c0);
                        DOT12L(xt, &w1t[4 * j], &w2t[4 * j], wt, a1, b1, c1);
                    }
                }
                const float s1 = pair_sum(a0 + a1) + bv1;
                const float s2 = pair_sum(b0 + b1) + bv2;
                const float sa = pair_sum(c0 + c1) + bva;
                const float f1 = ftanh(s1);
                const float f2 = ftanh(s2);
                const float tg = fsig(sa);
                const float h  = f1 + tg * (f2 - f1);
                const _Float16 hv = (_Float16)h;
                const int pA = s & 1, pB = (s + 1) & 1;
                if (half == 0) {
                    if (L == 0) xc[pA][1][n] = hv; else xc[pA][2][n] = hv;
                    if (s == TSTEPS - 1) hn[HOFF + n] = h;
                } else {
                    if (L == 0) xc[pB][0][64 + n] = hv; else xc[pB][1][135 + n] = hv;
                }
            }
            __syncthreads();
        }
    } else {
        // ============== CLONE 2: pure L2, units 224-255 (all-reg) ==============
        const int n = unit - 224;                 // 0..31
        const float* W1p = P.W1[2];
        const float* W2p = P.W2[2];
        const float* Wap = P.Wa[2];
        const float* Wbp = P.Wb[2];
        const unsigned int* mkp = P.msk[2];
        const int nK   = n * 121;
        const int koff = 64 * half;

        half2v w1o_[16], w1t_[16], w2o_[16], w2t_[16], wao_[16], wat_[16];
#pragma unroll
        for (int j = 0; j < 4; ++j) {
#pragma unroll
            for (int e = 0; e < 4; ++e) {
                const int co = koff + (2 * j + up) * 8 + 2 * e;
                const int ct = koff + (2 * j + 1 - up) * 8 + 2 * e;
                w1o_[j * 4 + e] = fold2(W1p, mkp, nK, 121, co);
                w1t_[j * 4 + e] = fold2(W1p, mkp, nK, 121, ct);
                w2o_[j * 4 + e] = fold2(W2p, mkp, nK, 121, co);
                w2t_[j * 4 + e] = fold2(W2p, mkp, nK, 121, ct);
                wao_[j * 4 + e] = na2(Wap, Wbp, nK, 121, co);
                wat_[j * 4 + e] = na2(Wap, Wbp, nK, 121, ct);
            }
        }
        const float bv1 = P.b1[2][n];
        const float bv2 = P.b2[2][n];
        const float bva = P.ba[2][n] + P.bb[2][n];

        // x staging (wave 7 owns it): init x(0), prefetch x(1)
        const int xlane = tid - 448;
        float xpend = 0.0f;
        xc[0][0][xlane] = (_Float16)P.x[(rb + 0) * 64 + xlane];
        xpend           = P.x[(rb + 1) * 64 + xlane];
        __syncthreads();   // barrier #2

        for (int tick = 0; tick < TSTEPS + 2; ++tick) {
            WINDOW_BLOCK(;, DOJOB(tid - 192);)
            // stage x(tick+1), prefetch x(tick+2)
            if (tick + 1 < TSTEPS)
                xc[(tick + 1) & 1][0][xlane] = (_Float16)xpend;
            if (tick + 2 < TSTEPS)
                xpend = P.x[(rb + (tick + 2)) * 64 + xlane];

            const int s = tick - 2;
            if (s >= 0 && s < TSTEPS) {
                const _Float16* srcp = &xc[s & 1][2][koff];
                float a0 = 0.f, a1 = 0.f, b0 = 0.f, b1 = 0.f, c0 = 0.f, c1 = 0.f;
#pragma unroll
                for (int j = 0; j < 4; ++j) {
                    const half8v xo = *(const half8v*)(srcp + (2 * j + up) * 8);
                    const half8v xt = dpp_xor2(xo);
                    DOT12R(xo, &w1o_[4 * j], &w2o_[4 * j], &wao_[4 * j], a0, b0, c0);
                    DOT12R(xt, &w1t_[4 * j], &w2t_[4 * j], &wat_[4 * j], a1, b1, c1);
                }
                const float s1 = pair_sum(a0 + a1) + bv1;
                const float s2 = pair_sum(b0 + b1) + bv2;
                const float sa = pair_sum(c0 + c1) + bva;
                const float f1 = ftanh(s1);
                const float f2 = ftanh(s2);
                const float tg = fsig(sa);
                const float h  = f1 + tg * (f2 - f1);
                const _Float16 hv = (_Float16)h;
                const int pB = (s + 1) & 1;
                if (half == 0) {
                    if (s == TSTEPS - 1) hn[224 + n] = h;
                } else {
                    xc[pB][2][89 + n] = hv;
                }
            }
            __syncthreads();
        }
    }

    // ---- FC epilogue: out[b][o] = dot(hn, fcW[o,:]) + fcb[o], K-split pair ----
    {
        const int o = unit;
        const float4* wr = (const float4*)(P.fcW + (size_t)o * 256 + half * 128);
        const float4* hr = (const float4*)(hn + half * 128);
        float acc = half ? 0.0f : P.fcb[o];
#pragma unroll 8
        for (int d = 0; d < 32; ++d) {
            const float4 a = hr[d];
            const float4 w = wr[d];
            acc += a.x * w.x + a.y * w.y + a.z * w.z + a.w * w.w;
        }
        acc = pair_sum(acc);
        if (half == 0) out[(size_t)b * 256 + o] = acc;
    }
}

extern "C" void kernel_launch(void* const* d_in, const int* in_sizes, int n_in,
                              void* d_out, int out_size, void* d_ws, size_t ws_size,
                              hipStream_t stream) {
    (void)in_sizes; (void)n_in; (void)out_size; (void)d_ws; (void)ws_size;
    Ptrs P;
    P.x = (const float*)d_in[0];
    for (int l = 0; l < 3; ++l) {
        const int base = 1 + l * 9;
        P.msk[l] = (const unsigned int*)d_in[base + 0];
        P.W1[l]  = (const float*)d_in[base + 1];
        P.W2[l]  = (const float*)d_in[base + 2];
        P.Wa[l]  = (const float*)d_in[base + 3];
        P.Wb[l]  = (const float*)d_in[base + 4];
        P.b1[l]  = (const float*)d_in[base + 5];
        P.b2[l]  = (const float*)d_in[base + 6];
        P.ba[l]  = (const float*)d_in[base + 7];
        P.bb[l]  = (const float*)d_in[base + 8];
    }
    P.fcW = (const float*)d_in[28];
    P.fcb = (const float*)d_in[29];

    hipLaunchKernelGGL(cfc_kernel, dim3(NBLK), dim3(NTHR), 0, stream,
                       P, (float*)d_out);
}